// Round 2
// baseline (2497.000 us; speedup 1.0000x reference)
//
#include <hip/hip_runtime.h>

#define NN 50000
#define NE 800000

__device__ __forceinline__ float silu_f(float v) {
    return v * (1.0f / (1.0f + __expf(-v)));
}

// ---------------- embedding: h64 = h @ emb_w + emb_b  (N x 16 -> N x 64)
__global__ __launch_bounds__(256, 4) void k_embed(const float* __restrict__ h,
        const float* __restrict__ w, const float* __restrict__ b,
        float* __restrict__ h64) {
    int n = blockIdx.x * 256 + threadIdx.x;
    if (n >= NN) return;
    const float4* h4 = (const float4*)(h + (long)n * 16);
    float in[16];
    #pragma unroll
    for (int c = 0; c < 4; ++c) {
        float4 v = h4[c];
        in[4*c+0] = v.x; in[4*c+1] = v.y; in[4*c+2] = v.z; in[4*c+3] = v.w;
    }
    float acc[64];
    #pragma unroll
    for (int j = 0; j < 64; ++j) acc[j] = b[j];
    #pragma unroll
    for (int k = 0; k < 16; ++k) {
        #pragma unroll
        for (int j = 0; j < 64; ++j) acc[j] = fmaf(in[k], w[k*64 + j], acc[j]);
    }
    float4* o4 = (float4*)(h64 + (long)n * 64);
    #pragma unroll
    for (int c = 0; c < 16; ++c)
        o4[c] = make_float4(acc[4*c+0], acc[4*c+1], acc[4*c+2], acc[4*c+3]);
}

// ---------------- per-edge squared distance from node positions
__global__ __launch_bounds__(256, 4) void k_radial(const float* __restrict__ x,
        const int* __restrict__ row, const int* __restrict__ col,
        float* __restrict__ radial) {
    int e = blockIdx.x * 256 + threadIdx.x;
    if (e >= NE) return;
    int r = row[e], c = col[e];
    float dx = x[r*3+0] - x[c*3+0];
    float dy = x[r*3+1] - x[c*3+1];
    float dz = x[r*3+2] - x[c*3+2];
    radial[e] = dx*dx + dy*dy + dz*dz;
}

// ---------------- P = h64 @ w1[0:64] + b1 ; Q = h64 @ w1[64:128]
__global__ __launch_bounds__(256, 2) void k_pq(const float* __restrict__ h64,
        const float* __restrict__ w1, const float* __restrict__ b1,
        float* __restrict__ Pb, float* __restrict__ Qb) {
    int n = blockIdx.x * 256 + threadIdx.x;
    if (n >= NN) return;
    const float4* in4 = (const float4*)(h64 + (long)n * 64);
    float in[64];
    #pragma unroll
    for (int c = 0; c < 16; ++c) {
        float4 v = in4[c];
        in[4*c+0]=v.x; in[4*c+1]=v.y; in[4*c+2]=v.z; in[4*c+3]=v.w;
    }
    float acc[64];
    #pragma unroll
    for (int j = 0; j < 64; ++j) acc[j] = b1[j];
    #pragma unroll
    for (int k = 0; k < 64; ++k) {
        #pragma unroll
        for (int j = 0; j < 64; ++j) acc[j] = fmaf(in[k], w1[k*64+j], acc[j]);
    }
    float4* p4 = (float4*)(Pb + (long)n*64);
    #pragma unroll
    for (int c = 0; c < 16; ++c)
        p4[c] = make_float4(acc[4*c+0],acc[4*c+1],acc[4*c+2],acc[4*c+3]);
    #pragma unroll
    for (int j = 0; j < 64; ++j) acc[j] = 0.0f;
    const float* w1b = w1 + 64*64;
    #pragma unroll
    for (int k = 0; k < 64; ++k) {
        #pragma unroll
        for (int j = 0; j < 64; ++j) acc[j] = fmaf(in[k], w1b[k*64+j], acc[j]);
    }
    float4* q4 = (float4*)(Qb + (long)n*64);
    #pragma unroll
    for (int c = 0; c < 16; ++c)
        q4[c] = make_float4(acc[4*c+0],acc[4*c+1],acc[4*c+2],acc[4*c+3]);
}

// ---------------- edge MLP (layer1 decomposed) + coalesced atomic segment-sum
__global__ __launch_bounds__(256, 2) void k_edge(
        const float* __restrict__ Pb, const float* __restrict__ Qb,
        const float* __restrict__ radial, const float* __restrict__ dist0,
        const int* __restrict__ row, const int* __restrict__ col,
        const float* __restrict__ w1t,   // rows 128,129 of w1: [2][64]
        const float* __restrict__ w2,    // [64][64]
        const float* __restrict__ b2,    // [64]
        float* __restrict__ agg) {
    __shared__ float s_t[4][16*66];
    int e = blockIdx.x * 256 + threadIdx.x;     // NE % 256 == 0, no guard
    int lane = threadIdx.x & 63;
    float* st = s_t[threadIdx.x >> 6];
    int r = row[e], c = col[e];
    float rad = radial[e], d0 = dist0[e];
    const float4* Pr = (const float4*)(Pb + (long)r * 64);
    const float4* Qc = (const float4*)(Qb + (long)c * 64);
    float hid[64];
    #pragma unroll
    for (int kc = 0; kc < 16; ++kc) {
        float4 pv = Pr[kc];
        float4 qv = Qc[kc];
        hid[4*kc+0] = pv.x + qv.x + rad * w1t[4*kc+0] + d0 * w1t[64 + 4*kc+0];
        hid[4*kc+1] = pv.y + qv.y + rad * w1t[4*kc+1] + d0 * w1t[64 + 4*kc+1];
        hid[4*kc+2] = pv.z + qv.z + rad * w1t[4*kc+2] + d0 * w1t[64 + 4*kc+2];
        hid[4*kc+3] = pv.w + qv.w + rad * w1t[4*kc+3] + d0 * w1t[64 + 4*kc+3];
    }
    #pragma unroll
    for (int j = 0; j < 64; ++j) hid[j] = silu_f(hid[j]);
    #pragma unroll 1
    for (int hf = 0; hf < 2; ++hf) {
        float acc[32];
        #pragma unroll
        for (int j = 0; j < 32; ++j) acc[j] = b2[hf*32 + j];
        #pragma unroll
        for (int k = 0; k < 64; ++k) {
            #pragma unroll
            for (int j = 0; j < 32; ++j)
                acc[j] = fmaf(hid[k], w2[k*64 + hf*32 + j], acc[j]);
        }
        #pragma unroll
        for (int j = 0; j < 32; ++j) acc[j] = silu_f(acc[j]);
        #pragma unroll 1
        for (int cc = 0; cc < 2; ++cc) {
            #pragma unroll
            for (int f = 0; f < 16; ++f) st[f*66 + lane] = acc[cc*16 + f];
            __syncthreads();
            int f = lane & 15, eg = lane >> 4;
            int fbase = hf*32 + cc*16 + f;
            #pragma unroll
            for (int g = 0; g < 16; ++g) {
                int le = g*4 + eg;
                float v = st[f*66 + le];
                int rr = __shfl(r, le);
                atomicAdd(&agg[(long)rr*64 + fbase], v);
            }
            __syncthreads();
        }
    }
}

// ---------------- node MLP: h += silu([h, agg/100] @ w1 + b1) @ w2 + b2
__global__ __launch_bounds__(256, 2) void k_node(float* __restrict__ h64,
        const float* __restrict__ agg,
        const float* __restrict__ w1,  // [128][64]
        const float* __restrict__ b1,
        const float* __restrict__ w2,  // [64][64]
        const float* __restrict__ b2) {
    int n = blockIdx.x * 256 + threadIdx.x;
    if (n >= NN) return;
    const float4* h4 = (const float4*)(h64 + (long)n * 64);
    const float4* a4 = (const float4*)(agg + (long)n * 64);
    float in[64];
    #pragma unroll
    for (int c = 0; c < 16; ++c) {
        float4 v = h4[c];
        in[4*c+0]=v.x; in[4*c+1]=v.y; in[4*c+2]=v.z; in[4*c+3]=v.w;
    }
    float hid[64];
    #pragma unroll
    for (int j = 0; j < 64; ++j) hid[j] = b1[j];
    #pragma unroll
    for (int k = 0; k < 64; ++k) {
        #pragma unroll
        for (int j = 0; j < 64; ++j) hid[j] = fmaf(in[k], w1[k*64+j], hid[j]);
    }
    const float* w1b = w1 + 64*64;
    #pragma unroll
    for (int c = 0; c < 16; ++c) {
        float4 v = a4[c];
        float s0 = v.x*0.01f, s1 = v.y*0.01f, s2 = v.z*0.01f, s3 = v.w*0.01f;
        #pragma unroll
        for (int j = 0; j < 64; ++j) hid[j] = fmaf(s0, w1b[(4*c+0)*64+j], hid[j]);
        #pragma unroll
        for (int j = 0; j < 64; ++j) hid[j] = fmaf(s1, w1b[(4*c+1)*64+j], hid[j]);
        #pragma unroll
        for (int j = 0; j < 64; ++j) hid[j] = fmaf(s2, w1b[(4*c+2)*64+j], hid[j]);
        #pragma unroll
        for (int j = 0; j < 64; ++j) hid[j] = fmaf(s3, w1b[(4*c+3)*64+j], hid[j]);
    }
    #pragma unroll
    for (int j = 0; j < 64; ++j) hid[j] = silu_f(hid[j]);
    float acc[64];
    #pragma unroll
    for (int j = 0; j < 64; ++j) acc[j] = b2[j];
    #pragma unroll
    for (int k = 0; k < 64; ++k) {
        #pragma unroll
        for (int j = 0; j < 64; ++j) acc[j] = fmaf(hid[k], w2[k*64+j], acc[j]);
    }
    float4* o4 = (float4*)(h64 + (long)n * 64);
    #pragma unroll
    for (int c = 0; c < 16; ++c) {
        float4 v = o4[c];      // reload h row (residual); keeps peak VGPR lower
        v.x += acc[4*c+0]; v.y += acc[4*c+1]; v.z += acc[4*c+2]; v.w += acc[4*c+3];
        o4[c] = v;
    }
}

// ---------------- coordinate update edge kernel
// Reads block-start snapshot x_old (never written here), accumulates into
// x_new (pre-initialized to x_old by a D2D copy) -> no read/write race.
__global__ __launch_bounds__(256, 2) void k_coord(
        const float* __restrict__ Pb, const float* __restrict__ Qb,
        const float* __restrict__ radial, const float* __restrict__ dist0,
        const int* __restrict__ row, const int* __restrict__ col,
        const float* __restrict__ w1t, const float* __restrict__ w2,
        const float* __restrict__ b2, const float* __restrict__ w3,
        const float* __restrict__ x_old,
        float* __restrict__ x_new) {
    int e = blockIdx.x * 256 + threadIdx.x;
    int r = row[e], c = col[e];
    float rad = radial[e], d0 = dist0[e];
    const float4* Pr = (const float4*)(Pb + (long)r * 64);
    const float4* Qc = (const float4*)(Qb + (long)c * 64);
    float hid[64];
    #pragma unroll
    for (int kc = 0; kc < 16; ++kc) {
        float4 pv = Pr[kc];
        float4 qv = Qc[kc];
        hid[4*kc+0] = pv.x + qv.x + rad * w1t[4*kc+0] + d0 * w1t[64 + 4*kc+0];
        hid[4*kc+1] = pv.y + qv.y + rad * w1t[4*kc+1] + d0 * w1t[64 + 4*kc+1];
        hid[4*kc+2] = pv.z + qv.z + rad * w1t[4*kc+2] + d0 * w1t[64 + 4*kc+2];
        hid[4*kc+3] = pv.w + qv.w + rad * w1t[4*kc+3] + d0 * w1t[64 + 4*kc+3];
    }
    #pragma unroll
    for (int j = 0; j < 64; ++j) hid[j] = silu_f(hid[j]);
    float phi = 0.0f;
    #pragma unroll 1
    for (int hf = 0; hf < 2; ++hf) {
        float acc[32];
        #pragma unroll
        for (int j = 0; j < 32; ++j) acc[j] = b2[hf*32 + j];
        #pragma unroll
        for (int k = 0; k < 64; ++k) {
            #pragma unroll
            for (int j = 0; j < 32; ++j)
                acc[j] = fmaf(hid[k], w2[k*64 + hf*32 + j], acc[j]);
        }
        #pragma unroll
        for (int j = 0; j < 32; ++j) phi = fmaf(silu_f(acc[j]), w3[hf*32 + j], phi);
    }
    phi *= 0.01f;   // 1/NORM_FACTOR folded in
    // recompute normalized coord_diff from the block-start snapshot
    float dx = x_old[r*3+0] - x_old[c*3+0];
    float dy = x_old[r*3+1] - x_old[c*3+1];
    float dz = x_old[r*3+2] - x_old[c*3+2];
    float inv = phi / (sqrtf(rad + 1e-8f) + 1.0f);
    atomicAdd(&x_new[r*3+0], dx * inv);
    atomicAdd(&x_new[r*3+1], dy * inv);
    atomicAdd(&x_new[r*3+2], dz * inv);
}

// ---------------- output projection: out = h64 @ out_w + out_b  (N x 64 -> N x 16)
__global__ __launch_bounds__(256, 4) void k_out(const float* __restrict__ h64,
        const float* __restrict__ w, const float* __restrict__ b,
        float* __restrict__ out) {
    int n = blockIdx.x * 256 + threadIdx.x;
    if (n >= NN) return;
    float acc[16];
    #pragma unroll
    for (int j = 0; j < 16; ++j) acc[j] = b[j];
    const float4* h4 = (const float4*)(h64 + (long)n*64);
    #pragma unroll
    for (int c = 0; c < 16; ++c) {
        float4 v = h4[c];
        float vv[4] = {v.x, v.y, v.z, v.w};
        #pragma unroll
        for (int t = 0; t < 4; ++t) {
            #pragma unroll
            for (int j = 0; j < 16; ++j)
                acc[j] = fmaf(vv[t], w[(4*c+t)*16 + j], acc[j]);
        }
    }
    float4* o4 = (float4*)(out + (long)n*16);
    #pragma unroll
    for (int cq = 0; cq < 4; ++cq)
        o4[cq] = make_float4(acc[4*cq+0],acc[4*cq+1],acc[4*cq+2],acc[4*cq+3]);
}

extern "C" void kernel_launch(void* const* d_in, const int* in_sizes, int n_in,
                              void* d_out, int out_size, void* d_ws, size_t ws_size,
                              hipStream_t stream) {
    const float* h_in  = (const float*)d_in[0];
    const float* x_in  = (const float*)d_in[1];
    const int*   row   = (const int*)d_in[2];
    const int*   col   = (const int*)d_in[3];
    const float* emb_w = (const float*)d_in[4];
    const float* emb_b = (const float*)d_in[5];
    const float* out_w = (const float*)d_in[6];
    const float* out_b = (const float*)d_in[7];
    const float* e_w1  = (const float*)d_in[8];
    const float* e_b1  = (const float*)d_in[9];
    const float* e_w2  = (const float*)d_in[10];
    const float* e_b2  = (const float*)d_in[11];
    const float* n_w1  = (const float*)d_in[12];
    const float* n_b1  = (const float*)d_in[13];
    const float* n_w2  = (const float*)d_in[14];
    const float* n_b2  = (const float*)d_in[15];
    const float* q_w1  = (const float*)d_in[16];
    const float* q_b1  = (const float*)d_in[17];
    const float* q_w2  = (const float*)d_in[18];
    const float* q_b2  = (const float*)d_in[19];
    const float* q_w3  = (const float*)d_in[20];

    // workspace layout (floats): h64, Pb, Qb, agg (N*64 each), dist0, rad1 (E each), xA (N*3)
    size_t need = ((size_t)NN*64*4 + (size_t)NE*2 + (size_t)NN*3) * sizeof(float);
    if (ws_size < need) return;   // diagnostic guard: clean failure, no OOB writes

    float* ws    = (float*)d_ws;
    float* h64   = ws;                          // N*64
    float* Pb    = h64   + (size_t)NN*64;       // N*64
    float* Qb    = Pb    + (size_t)NN*64;       // N*64
    float* agg   = Qb    + (size_t)NN*64;       // N*64
    float* dist0 = agg   + (size_t)NN*64;       // E
    float* rad1  = dist0 + (size_t)NE;          // E
    float* xA    = rad1  + (size_t)NE;          // N*3

    float* out_h = (float*)d_out;
    float* out_x = out_h + (size_t)NN*16;

    dim3 th(256);
    dim3 nb((NN + 255)/256);
    dim3 eb(NE/256);

    k_radial<<<eb, th, 0, stream>>>(x_in, row, col, dist0);
    k_embed<<<nb, th, 0, stream>>>(h_in, emb_w, emb_b, h64);

    for (int b = 0; b < 2; ++b) {
        const float* x_old;
        float*       x_new;
        const float* radp;
        if (b == 0) {
            x_old = x_in;  x_new = xA;    radp = dist0;
        } else {
            x_old = xA;    x_new = out_x; radp = rad1;
            k_radial<<<eb, th, 0, stream>>>(x_old, row, col, rad1);
        }
        for (int i = 0; i < 2; ++i) {
            int l = b*2 + i;
            k_pq<<<nb, th, 0, stream>>>(h64, e_w1 + (size_t)l*130*64,
                                        e_b1 + (size_t)l*64, Pb, Qb);
            hipMemsetAsync(agg, 0, (size_t)NN*64*sizeof(float), stream);
            k_edge<<<eb, th, 0, stream>>>(Pb, Qb, radp, dist0, row, col,
                    e_w1 + (size_t)l*130*64 + 128*64,
                    e_w2 + (size_t)l*64*64, e_b2 + (size_t)l*64, agg);
            k_node<<<nb, th, 0, stream>>>(h64, agg,
                    n_w1 + (size_t)l*128*64, n_b1 + (size_t)l*64,
                    n_w2 + (size_t)l*64*64, n_b2 + (size_t)l*64);
        }
        k_pq<<<nb, th, 0, stream>>>(h64, q_w1 + (size_t)b*130*64,
                                    q_b1 + (size_t)b*64, Pb, Qb);
        // x_new starts as a copy of x_old; k_coord adds the deltas atomically
        hipMemcpyAsync(x_new, x_old, (size_t)NN*3*sizeof(float),
                       hipMemcpyDeviceToDevice, stream);
        k_coord<<<eb, th, 0, stream>>>(Pb, Qb, radp, dist0, row, col,
                q_w1 + (size_t)b*130*64 + 128*64,
                q_w2 + (size_t)b*64*64, q_b2 + (size_t)b*64,
                q_w3 + (size_t)b*64, x_old, x_new);
    }
    k_out<<<nb, th, 0, stream>>>(h64, out_w, out_b, out_h);
}

// Round 3
// 2177.412 us; speedup vs baseline: 1.1468x; 1.1468x over previous
//
#include <hip/hip_runtime.h>

#define NN 50000
#define NE 800000

__device__ __forceinline__ float silu_f(float v) {
    return v * (1.0f / (1.0f + __expf(-v)));
}

// ---------------- embedding: h64 = h @ emb_w + emb_b  (N x 16 -> N x 64)
__global__ __launch_bounds__(256, 4) void k_embed(const float* __restrict__ h,
        const float* __restrict__ w, const float* __restrict__ b,
        float* __restrict__ h64) {
    int n = blockIdx.x * 256 + threadIdx.x;
    if (n >= NN) return;
    const float4* h4 = (const float4*)(h + (long)n * 16);
    float in[16];
    #pragma unroll
    for (int c = 0; c < 4; ++c) {
        float4 v = h4[c];
        in[4*c+0] = v.x; in[4*c+1] = v.y; in[4*c+2] = v.z; in[4*c+3] = v.w;
    }
    float acc[64];
    #pragma unroll
    for (int j = 0; j < 64; ++j) acc[j] = b[j];
    #pragma unroll
    for (int k = 0; k < 16; ++k) {
        #pragma unroll
        for (int j = 0; j < 64; ++j) acc[j] = fmaf(in[k], w[k*64 + j], acc[j]);
    }
    float4* o4 = (float4*)(h64 + (long)n * 64);
    #pragma unroll
    for (int c = 0; c < 16; ++c)
        o4[c] = make_float4(acc[4*c+0], acc[4*c+1], acc[4*c+2], acc[4*c+3]);
}

// ---------------- CSR-order build: histogram / scan / scatter ----------------
__global__ __launch_bounds__(256, 4) void k_hist(const int* __restrict__ row,
        int* __restrict__ deg) {
    int e = blockIdx.x * 256 + threadIdx.x;
    if (e < NE) atomicAdd(&deg[row[e]], 1);
}

// single-block exclusive scan of deg[0..NN) -> base[0..NN)
__global__ __launch_bounds__(256) void k_scan(const int* __restrict__ deg,
        int* __restrict__ base) {
    __shared__ int s[256];
    const int CH = (NN + 255) / 256;   // 196
    int t = threadIdx.x;
    int lo = t * CH, hi = min(lo + CH, NN);
    int sum = 0;
    for (int i = lo; i < hi; ++i) sum += deg[i];
    s[t] = sum;
    __syncthreads();
    #pragma unroll
    for (int d = 1; d < 256; d <<= 1) {
        int v = (t >= d) ? s[t - d] : 0;
        __syncthreads();
        s[t] += v;
        __syncthreads();
    }
    int run = s[t] - sum;              // exclusive prefix
    for (int i = lo; i < hi; ++i) { base[i] = run; run += deg[i]; }
}

// scatter edges into row-sorted order (destroys base: it becomes end offsets)
__global__ __launch_bounds__(256, 4) void k_scatter(const int* __restrict__ row,
        const int* __restrict__ col, int* __restrict__ base,
        int* __restrict__ rowS, int* __restrict__ colS) {
    int e = blockIdx.x * 256 + threadIdx.x;
    if (e >= NE) return;
    int r = row[e];
    int p = atomicAdd(&base[r], 1);
    rowS[p] = r;
    colS[p] = col[e];
}

// ---------------- per-edge squared distance (sorted edge space)
__global__ __launch_bounds__(256, 4) void k_radial(const float* __restrict__ x,
        const int* __restrict__ rowS, const int* __restrict__ colS,
        float* __restrict__ radial) {
    int e = blockIdx.x * 256 + threadIdx.x;
    if (e >= NE) return;
    int r = rowS[e], c = colS[e];
    float dx = x[r*3+0] - x[c*3+0];
    float dy = x[r*3+1] - x[c*3+1];
    float dz = x[r*3+2] - x[c*3+2];
    radial[e] = dx*dx + dy*dy + dz*dz;
}

// ---------------- P = h64 @ w1[0:64] + b1 ; Q = h64 @ w1[64:128]
__global__ __launch_bounds__(256, 2) void k_pq(const float* __restrict__ h64,
        const float* __restrict__ w1, const float* __restrict__ b1,
        float* __restrict__ Pb, float* __restrict__ Qb) {
    int n = blockIdx.x * 256 + threadIdx.x;
    if (n >= NN) return;
    const float4* in4 = (const float4*)(h64 + (long)n * 64);
    float in[64];
    #pragma unroll
    for (int c = 0; c < 16; ++c) {
        float4 v = in4[c];
        in[4*c+0]=v.x; in[4*c+1]=v.y; in[4*c+2]=v.z; in[4*c+3]=v.w;
    }
    float acc[64];
    #pragma unroll
    for (int j = 0; j < 64; ++j) acc[j] = b1[j];
    #pragma unroll
    for (int k = 0; k < 64; ++k) {
        #pragma unroll
        for (int j = 0; j < 64; ++j) acc[j] = fmaf(in[k], w1[k*64+j], acc[j]);
    }
    float4* p4 = (float4*)(Pb + (long)n*64);
    #pragma unroll
    for (int c = 0; c < 16; ++c)
        p4[c] = make_float4(acc[4*c+0],acc[4*c+1],acc[4*c+2],acc[4*c+3]);
    #pragma unroll
    for (int j = 0; j < 64; ++j) acc[j] = 0.0f;
    const float* w1b = w1 + 64*64;
    #pragma unroll
    for (int k = 0; k < 64; ++k) {
        #pragma unroll
        for (int j = 0; j < 64; ++j) acc[j] = fmaf(in[k], w1b[k*64+j], acc[j]);
    }
    float4* q4 = (float4*)(Qb + (long)n*64);
    #pragma unroll
    for (int c = 0; c < 16; ++c)
        q4[c] = make_float4(acc[4*c+0],acc[4*c+1],acc[4*c+2],acc[4*c+3]);
}

// ---------------- edge MLP (sorted) + run-length-compressed atomic segment-sum
__global__ __launch_bounds__(256, 2) void k_edge(
        const float* __restrict__ Pb, const float* __restrict__ Qb,
        const float* __restrict__ radial, const float* __restrict__ dist0,
        const int* __restrict__ rowS, const int* __restrict__ colS,
        const float* __restrict__ w1t,   // rows 128,129 of w1: [2][64]
        const float* __restrict__ w2,    // [64][64]
        const float* __restrict__ b2,    // [64]
        float* __restrict__ agg) {
    __shared__ float s_t[4][16*67];
    int e = blockIdx.x * 256 + threadIdx.x;     // NE % 256 == 0, no guard
    int lane = threadIdx.x & 63;
    float* st = s_t[threadIdx.x >> 6];
    int r = rowS[e], c = colS[e];
    float rad = radial[e], d0 = dist0[e];
    const float4* Pr = (const float4*)(Pb + (long)r * 64);
    const float4* Qc = (const float4*)(Qb + (long)c * 64);
    float hid[64];
    #pragma unroll
    for (int kc = 0; kc < 16; ++kc) {
        float4 pv = Pr[kc];
        float4 qv = Qc[kc];
        hid[4*kc+0] = pv.x + qv.x + rad * w1t[4*kc+0] + d0 * w1t[64 + 4*kc+0];
        hid[4*kc+1] = pv.y + qv.y + rad * w1t[4*kc+1] + d0 * w1t[64 + 4*kc+1];
        hid[4*kc+2] = pv.z + qv.z + rad * w1t[4*kc+2] + d0 * w1t[64 + 4*kc+2];
        hid[4*kc+3] = pv.w + qv.w + rad * w1t[4*kc+3] + d0 * w1t[64 + 4*kc+3];
    }
    #pragma unroll
    for (int j = 0; j < 64; ++j) hid[j] = silu_f(hid[j]);
    #pragma unroll 1
    for (int hf = 0; hf < 2; ++hf) {
        float acc[32];
        #pragma unroll
        for (int j = 0; j < 32; ++j) acc[j] = b2[hf*32 + j];
        #pragma unroll
        for (int k = 0; k < 64; ++k) {
            #pragma unroll
            for (int j = 0; j < 32; ++j)
                acc[j] = fmaf(hid[k], w2[k*64 + hf*32 + j], acc[j]);
        }
        #pragma unroll
        for (int j = 0; j < 32; ++j) acc[j] = silu_f(acc[j]);
        #pragma unroll 1
        for (int cc = 0; cc < 2; ++cc) {
            #pragma unroll
            for (int f = 0; f < 16; ++f) st[f*67 + lane] = acc[cc*16 + f];
            __syncthreads();
            // lane (f, eg) walks 16 CONSECUTIVE sorted edges, accumulating
            // equal-row runs in a register; flushes ~2 atomics (deg ~16)
            int f = lane & 15, eg = lane >> 4;
            int fglob = hf*32 + cc*16 + f;
            int lebase = eg*16;
            float racc = 0.0f;
            int cur_r = __shfl(r, lebase);
            #pragma unroll
            for (int t = 0; t < 16; ++t) {
                int le = lebase + t;
                float v = st[f*67 + le];
                int rr = __shfl(r, le);
                if (rr != cur_r) {
                    atomicAdd(&agg[(long)cur_r*64 + fglob], racc);
                    racc = 0.0f; cur_r = rr;
                }
                racc += v;
            }
            atomicAdd(&agg[(long)cur_r*64 + fglob], racc);
            __syncthreads();
        }
    }
}

// ---------------- node MLP: h += silu([h, agg/100] @ w1 + b1) @ w2 + b2
__global__ __launch_bounds__(256, 2) void k_node(float* __restrict__ h64,
        const float* __restrict__ agg,
        const float* __restrict__ w1,  // [128][64]
        const float* __restrict__ b1,
        const float* __restrict__ w2,  // [64][64]
        const float* __restrict__ b2) {
    int n = blockIdx.x * 256 + threadIdx.x;
    if (n >= NN) return;
    const float4* h4 = (const float4*)(h64 + (long)n * 64);
    const float4* a4 = (const float4*)(agg + (long)n * 64);
    float in[64];
    #pragma unroll
    for (int c = 0; c < 16; ++c) {
        float4 v = h4[c];
        in[4*c+0]=v.x; in[4*c+1]=v.y; in[4*c+2]=v.z; in[4*c+3]=v.w;
    }
    float hid[64];
    #pragma unroll
    for (int j = 0; j < 64; ++j) hid[j] = b1[j];
    #pragma unroll
    for (int k = 0; k < 64; ++k) {
        #pragma unroll
        for (int j = 0; j < 64; ++j) hid[j] = fmaf(in[k], w1[k*64+j], hid[j]);
    }
    const float* w1b = w1 + 64*64;
    #pragma unroll
    for (int c = 0; c < 16; ++c) {
        float4 v = a4[c];
        float s0 = v.x*0.01f, s1 = v.y*0.01f, s2 = v.z*0.01f, s3 = v.w*0.01f;
        #pragma unroll
        for (int j = 0; j < 64; ++j) hid[j] = fmaf(s0, w1b[(4*c+0)*64+j], hid[j]);
        #pragma unroll
        for (int j = 0; j < 64; ++j) hid[j] = fmaf(s1, w1b[(4*c+1)*64+j], hid[j]);
        #pragma unroll
        for (int j = 0; j < 64; ++j) hid[j] = fmaf(s2, w1b[(4*c+2)*64+j], hid[j]);
        #pragma unroll
        for (int j = 0; j < 64; ++j) hid[j] = fmaf(s3, w1b[(4*c+3)*64+j], hid[j]);
    }
    #pragma unroll
    for (int j = 0; j < 64; ++j) hid[j] = silu_f(hid[j]);
    float acc[64];
    #pragma unroll
    for (int j = 0; j < 64; ++j) acc[j] = b2[j];
    #pragma unroll
    for (int k = 0; k < 64; ++k) {
        #pragma unroll
        for (int j = 0; j < 64; ++j) acc[j] = fmaf(hid[k], w2[k*64+j], acc[j]);
    }
    float4* o4 = (float4*)(h64 + (long)n * 64);
    #pragma unroll
    for (int c = 0; c < 16; ++c) {
        float4 v = o4[c];
        v.x += acc[4*c+0]; v.y += acc[4*c+1]; v.z += acc[4*c+2]; v.w += acc[4*c+3];
        o4[c] = v;
    }
}

// ---------------- coordinate update edge kernel (sorted, segmented-scan atomics)
__global__ __launch_bounds__(256, 2) void k_coord(
        const float* __restrict__ Pb, const float* __restrict__ Qb,
        const float* __restrict__ radial, const float* __restrict__ dist0,
        const int* __restrict__ rowS, const int* __restrict__ colS,
        const float* __restrict__ w1t, const float* __restrict__ w2,
        const float* __restrict__ b2, const float* __restrict__ w3,
        const float* __restrict__ x_old,
        float* __restrict__ x_new) {
    int e = blockIdx.x * 256 + threadIdx.x;
    int lane = threadIdx.x & 63;
    int r = rowS[e], c = colS[e];
    float rad = radial[e], d0 = dist0[e];
    const float4* Pr = (const float4*)(Pb + (long)r * 64);
    const float4* Qc = (const float4*)(Qb + (long)c * 64);
    float hid[64];
    #pragma unroll
    for (int kc = 0; kc < 16; ++kc) {
        float4 pv = Pr[kc];
        float4 qv = Qc[kc];
        hid[4*kc+0] = pv.x + qv.x + rad * w1t[4*kc+0] + d0 * w1t[64 + 4*kc+0];
        hid[4*kc+1] = pv.y + qv.y + rad * w1t[4*kc+1] + d0 * w1t[64 + 4*kc+1];
        hid[4*kc+2] = pv.z + qv.z + rad * w1t[4*kc+2] + d0 * w1t[64 + 4*kc+2];
        hid[4*kc+3] = pv.w + qv.w + rad * w1t[4*kc+3] + d0 * w1t[64 + 4*kc+3];
    }
    #pragma unroll
    for (int j = 0; j < 64; ++j) hid[j] = silu_f(hid[j]);
    float phi = 0.0f;
    #pragma unroll 1
    for (int hf = 0; hf < 2; ++hf) {
        float acc[32];
        #pragma unroll
        for (int j = 0; j < 32; ++j) acc[j] = b2[hf*32 + j];
        #pragma unroll
        for (int k = 0; k < 64; ++k) {
            #pragma unroll
            for (int j = 0; j < 32; ++j)
                acc[j] = fmaf(hid[k], w2[k*64 + hf*32 + j], acc[j]);
        }
        #pragma unroll
        for (int j = 0; j < 32; ++j) phi = fmaf(silu_f(acc[j]), w3[hf*32 + j], phi);
    }
    phi *= 0.01f;   // 1/NORM_FACTOR folded in
    float dx = x_old[r*3+0] - x_old[c*3+0];
    float dy = x_old[r*3+1] - x_old[c*3+1];
    float dz = x_old[r*3+2] - x_old[c*3+2];
    float inv = phi / (sqrtf(rad + 1e-8f) + 1.0f);
    float tx = dx * inv, ty = dy * inv, tz = dz * inv;
    // wave-level segmented reduction over equal-row runs (rows are sorted)
    int rprev = __shfl_up(r, 1);
    bool head = (lane == 0) || (rprev != r);
    unsigned long long hm = __ballot(head);
    int runid = __popcll(hm & ((2ull << lane) - 1ull));
    #pragma unroll
    for (int d = 1; d < 64; d <<= 1) {
        float ox = __shfl_up(tx, d);
        float oy = __shfl_up(ty, d);
        float oz = __shfl_up(tz, d);
        int orid = __shfl_up(runid, d);
        if (lane >= d && orid == runid) { tx += ox; ty += oy; tz += oz; }
    }
    int rid_next = __shfl_down(runid, 1);
    bool tail = (lane == 63) || (rid_next != runid);
    if (tail) {
        atomicAdd(&x_new[r*3+0], tx);
        atomicAdd(&x_new[r*3+1], ty);
        atomicAdd(&x_new[r*3+2], tz);
    }
}

// ---------------- output projection: out = h64 @ out_w + out_b  (N x 64 -> N x 16)
__global__ __launch_bounds__(256, 4) void k_out(const float* __restrict__ h64,
        const float* __restrict__ w, const float* __restrict__ b,
        float* __restrict__ out) {
    int n = blockIdx.x * 256 + threadIdx.x;
    if (n >= NN) return;
    float acc[16];
    #pragma unroll
    for (int j = 0; j < 16; ++j) acc[j] = b[j];
    const float4* h4 = (const float4*)(h64 + (long)n*64);
    #pragma unroll
    for (int c = 0; c < 16; ++c) {
        float4 v = h4[c];
        float vv[4] = {v.x, v.y, v.z, v.w};
        #pragma unroll
        for (int t = 0; t < 4; ++t) {
            #pragma unroll
            for (int j = 0; j < 16; ++j)
                acc[j] = fmaf(vv[t], w[(4*c+t)*16 + j], acc[j]);
        }
    }
    float4* o4 = (float4*)(out + (long)n*16);
    #pragma unroll
    for (int cq = 0; cq < 4; ++cq)
        o4[cq] = make_float4(acc[4*cq+0],acc[4*cq+1],acc[4*cq+2],acc[4*cq+3]);
}

extern "C" void kernel_launch(void* const* d_in, const int* in_sizes, int n_in,
                              void* d_out, int out_size, void* d_ws, size_t ws_size,
                              hipStream_t stream) {
    const float* h_in  = (const float*)d_in[0];
    const float* x_in  = (const float*)d_in[1];
    const int*   row   = (const int*)d_in[2];
    const int*   col   = (const int*)d_in[3];
    const float* emb_w = (const float*)d_in[4];
    const float* emb_b = (const float*)d_in[5];
    const float* out_w = (const float*)d_in[6];
    const float* out_b = (const float*)d_in[7];
    const float* e_w1  = (const float*)d_in[8];
    const float* e_b1  = (const float*)d_in[9];
    const float* e_w2  = (const float*)d_in[10];
    const float* e_b2  = (const float*)d_in[11];
    const float* n_w1  = (const float*)d_in[12];
    const float* n_b1  = (const float*)d_in[13];
    const float* n_w2  = (const float*)d_in[14];
    const float* n_b2  = (const float*)d_in[15];
    const float* q_w1  = (const float*)d_in[16];
    const float* q_b1  = (const float*)d_in[17];
    const float* q_w2  = (const float*)d_in[18];
    const float* q_b2  = (const float*)d_in[19];
    const float* q_w3  = (const float*)d_in[20];

    // ws layout (4B units)
    size_t need = ((size_t)NN*64*4 + (size_t)NE*2 + (size_t)NN*3
                   + (size_t)NE*2 + (size_t)NN*2 + 64) * sizeof(float);
    if (ws_size < need) return;   // clean failure, no OOB writes

    float* ws    = (float*)d_ws;
    float* h64   = ws;                          // N*64
    float* Pb    = h64   + (size_t)NN*64;       // N*64
    float* Qb    = Pb    + (size_t)NN*64;       // N*64
    float* agg   = Qb    + (size_t)NN*64;       // N*64
    float* d0S   = agg   + (size_t)NN*64;       // E   (sorted)
    float* radS  = d0S   + (size_t)NE;          // E   (sorted)
    float* xA    = radS  + (size_t)NE;          // N*3
    int*   rowS  = (int*)(xA + (size_t)NN*3);   // E
    int*   colS  = rowS  + (size_t)NE;          // E
    int*   deg   = colS  + (size_t)NE;          // N
    int*   base  = deg   + (size_t)NN;          // N+1

    float* out_h = (float*)d_out;
    float* out_x = out_h + (size_t)NN*16;

    dim3 th(256);
    dim3 nb((NN + 255)/256);
    dim3 eb(NE/256);

    // ---- build row-sorted edge order (counting sort), every call ----
    hipMemsetAsync(deg, 0, (size_t)NN*sizeof(int), stream);
    k_hist<<<eb, th, 0, stream>>>(row, deg);
    k_scan<<<1, th, 0, stream>>>(deg, base);
    k_scatter<<<eb, th, 0, stream>>>(row, col, base, rowS, colS);

    k_radial<<<eb, th, 0, stream>>>(x_in, rowS, colS, d0S);
    k_embed<<<nb, th, 0, stream>>>(h_in, emb_w, emb_b, h64);

    for (int b = 0; b < 2; ++b) {
        const float* x_old;
        float*       x_new;
        const float* radp;
        if (b == 0) {
            x_old = x_in;  x_new = xA;    radp = d0S;
        } else {
            x_old = xA;    x_new = out_x; radp = radS;
            k_radial<<<eb, th, 0, stream>>>(x_old, rowS, colS, radS);
        }
        for (int i = 0; i < 2; ++i) {
            int l = b*2 + i;
            k_pq<<<nb, th, 0, stream>>>(h64, e_w1 + (size_t)l*130*64,
                                        e_b1 + (size_t)l*64, Pb, Qb);
            hipMemsetAsync(agg, 0, (size_t)NN*64*sizeof(float), stream);
            k_edge<<<eb, th, 0, stream>>>(Pb, Qb, radp, d0S, rowS, colS,
                    e_w1 + (size_t)l*130*64 + 128*64,
                    e_w2 + (size_t)l*64*64, e_b2 + (size_t)l*64, agg);
            k_node<<<nb, th, 0, stream>>>(h64, agg,
                    n_w1 + (size_t)l*128*64, n_b1 + (size_t)l*64,
                    n_w2 + (size_t)l*64*64, n_b2 + (size_t)l*64);
        }
        k_pq<<<nb, th, 0, stream>>>(h64, q_w1 + (size_t)b*130*64,
                                    q_b1 + (size_t)b*64, Pb, Qb);
        hipMemcpyAsync(x_new, x_old, (size_t)NN*3*sizeof(float),
                       hipMemcpyDeviceToDevice, stream);
        k_coord<<<eb, th, 0, stream>>>(Pb, Qb, radp, d0S, rowS, colS,
                q_w1 + (size_t)b*130*64 + 128*64,
                q_w2 + (size_t)b*64*64, q_b2 + (size_t)b*64,
                q_w3 + (size_t)b*64, x_old, x_new);
    }
    k_out<<<nb, th, 0, stream>>>(h64, out_w, out_b, out_h);
}

// Round 4
// 2016.200 us; speedup vs baseline: 1.2385x; 1.0800x over previous
//
#include <hip/hip_runtime.h>

#define NN 50000
#define NE 800000

typedef unsigned int  u32;
typedef unsigned short u16;
typedef __attribute__((ext_vector_type(8))) short short8;
typedef __attribute__((ext_vector_type(4))) float f32x4;

union ABfrag { uint2 u2[2]; uint4 u4; short8 s8; };

__device__ __forceinline__ float silu_f(float v) {
    return v * (1.0f / (1.0f + __expf(-v)));
}
__device__ __forceinline__ u32 bfr(float x) {   // f32 -> bf16 (RNE), low 16 bits
    u32 u = __float_as_uint(x);
    u += 0x7fffu + ((u >> 16) & 1u);
    return u >> 16;
}
__device__ __forceinline__ float bff(u32 h) { return __uint_as_float(h << 16); }

// ---------------- embedding: h64 = h @ emb_w + emb_b  (N x 16 -> N x 64)
__global__ __launch_bounds__(256, 4) void k_embed(const float* __restrict__ h,
        const float* __restrict__ w, const float* __restrict__ b,
        float* __restrict__ h64) {
    int n = blockIdx.x * 256 + threadIdx.x;
    if (n >= NN) return;
    const float4* h4 = (const float4*)(h + (long)n * 16);
    float in[16];
    #pragma unroll
    for (int c = 0; c < 4; ++c) {
        float4 v = h4[c];
        in[4*c+0] = v.x; in[4*c+1] = v.y; in[4*c+2] = v.z; in[4*c+3] = v.w;
    }
    float acc[64];
    #pragma unroll
    for (int j = 0; j < 64; ++j) acc[j] = b[j];
    #pragma unroll
    for (int k = 0; k < 16; ++k) {
        #pragma unroll
        for (int j = 0; j < 64; ++j) acc[j] = fmaf(in[k], w[k*64 + j], acc[j]);
    }
    float4* o4 = (float4*)(h64 + (long)n * 64);
    #pragma unroll
    for (int c = 0; c < 16; ++c)
        o4[c] = make_float4(acc[4*c+0], acc[4*c+1], acc[4*c+2], acc[4*c+3]);
}

// ---------------- CSR-order build: histogram / scan / scatter ----------------
__global__ __launch_bounds__(256, 4) void k_hist(const int* __restrict__ row,
        int* __restrict__ deg) {
    int e = blockIdx.x * 256 + threadIdx.x;
    if (e < NE) atomicAdd(&deg[row[e]], 1);
}

__global__ __launch_bounds__(256) void k_scan(const int* __restrict__ deg,
        int* __restrict__ base) {
    __shared__ int s[256];
    const int CH = (NN + 255) / 256;
    int t = threadIdx.x;
    int lo = t * CH, hi = min(lo + CH, NN);
    int sum = 0;
    for (int i = lo; i < hi; ++i) sum += deg[i];
    s[t] = sum;
    __syncthreads();
    #pragma unroll
    for (int d = 1; d < 256; d <<= 1) {
        int v = (t >= d) ? s[t - d] : 0;
        __syncthreads();
        s[t] += v;
        __syncthreads();
    }
    int run = s[t] - sum;
    for (int i = lo; i < hi; ++i) { base[i] = run; run += deg[i]; }
}

__global__ __launch_bounds__(256, 4) void k_scatter(const int* __restrict__ row,
        const int* __restrict__ col, int* __restrict__ base,
        int* __restrict__ rowS, int* __restrict__ colS) {
    int e = blockIdx.x * 256 + threadIdx.x;
    if (e >= NE) return;
    int r = row[e];
    int p = atomicAdd(&base[r], 1);
    rowS[p] = r;
    colS[p] = col[e];
}

// ---------------- per-edge squared distance (sorted edge space)
__global__ __launch_bounds__(256, 4) void k_radial(const float* __restrict__ x,
        const int* __restrict__ rowS, const int* __restrict__ colS,
        float* __restrict__ radial) {
    int e = blockIdx.x * 256 + threadIdx.x;
    if (e >= NE) return;
    int r = rowS[e], c = colS[e];
    float dx = x[r*3+0] - x[c*3+0];
    float dy = x[r*3+1] - x[c*3+1];
    float dz = x[r*3+2] - x[c*3+2];
    radial[e] = dx*dx + dy*dy + dz*dz;
}

// ---------------- w2 -> bf16 B-fragment order, 6 layers (4 edge + 2 coord)
// frag layout for mfma_f32_16x16x32_bf16: B col = lane&15, k = 8*(lane>>4)+j (+32*s)
__global__ __launch_bounds__(256, 4) void k_wconv(const float* __restrict__ e_w2,
        const float* __restrict__ q_w2, u16* __restrict__ w2f) {
    int t = blockIdx.x * 256 + threadIdx.x;
    if (t >= 6 * 4096) return;
    int L = t >> 12, rL = t & 4095;
    int j = rL & 7, lane = (rL >> 3) & 63, ns = rL >> 9;
    int n = ns >> 1, s = ns & 1;
    int k = 8 * (lane >> 4) + j + 32 * s;
    int colj = 16 * n + (lane & 15);
    const float* src = (L < 4) ? (e_w2 + (size_t)L * 4096)
                               : (q_w2 + (size_t)(L - 4) * 4096);
    w2f[t] = (u16)bfr(src[k * 64 + colj]);
}

// ---------------- P/Q: wave-uniform output quarter (weights stay in SGPRs)
__global__ __launch_bounds__(256, 4) void k_pq(const float* __restrict__ h64,
        const float* __restrict__ w1, const float* __restrict__ b1,
        float* __restrict__ Pb, float* __restrict__ Qb) {
    int w = threadIdx.x >> 6, lane = threadIdx.x & 63;
    int n = blockIdx.x * 64 + lane;
    if (n >= NN) return;
    const float4* in4 = (const float4*)(h64 + (long)n * 64);
    float accP[16], accQ[16];
    #pragma unroll
    for (int j = 0; j < 16; ++j) { accP[j] = b1[16*w + j]; accQ[j] = 0.0f; }
    const float* w1b = w1 + 64 * 64;
    #pragma unroll
    for (int c = 0; c < 16; ++c) {
        float4 f = in4[c];
        float vv[4] = {f.x, f.y, f.z, f.w};
        #pragma unroll
        for (int u = 0; u < 4; ++u) {
            int k = 4*c + u;
            #pragma unroll
            for (int j = 0; j < 16; ++j) {
                accP[j] = fmaf(vv[u], w1 [k*64 + 16*w + j], accP[j]);
                accQ[j] = fmaf(vv[u], w1b[k*64 + 16*w + j], accQ[j]);
            }
        }
    }
    float4* p4 = (float4*)(Pb + (long)n*64 + 16*w);
    float4* q4 = (float4*)(Qb + (long)n*64 + 16*w);
    #pragma unroll
    for (int c = 0; c < 4; ++c) {
        p4[c] = make_float4(accP[4*c+0], accP[4*c+1], accP[4*c+2], accP[4*c+3]);
        q4[c] = make_float4(accQ[4*c+0], accQ[4*c+1], accQ[4*c+2], accQ[4*c+3]);
    }
}

// ---------------- edge MLP: layer1 per-thread, layer2 via MFMA, coalesced agg
__global__ __launch_bounds__(256, 2) void k_edge(
        const float* __restrict__ Pb, const float* __restrict__ Qb,
        const float* __restrict__ radial, const float* __restrict__ dist0,
        const int* __restrict__ rowS, const int* __restrict__ colS,
        const float* __restrict__ w1t,   // rows 128,129 of w1: [2][64]
        const u16* __restrict__ w2f,     // this layer's 4096-entry B-frag block
        const float* __restrict__ b2,
        float* __restrict__ agg) {
    __shared__ u16 A_lds[4][4096];       // per-wave [64 edge][64 k] bf16, XOR-swz
    __shared__ u16 M_lds[4][64 * 68];    // per-wave [64 feat][68 edge] bf16
    int tid = threadIdx.x;
    int w = tid >> 6, lane = tid & 63;
    int e = blockIdx.x * 256 + w * 64 + lane;   // NE % 256 == 0
    u16* Aw = A_lds[w];
    u16* Mw = M_lds[w];
    int r = rowS[e], c = colS[e];
    float rad = radial[e], d0 = dist0[e];
    const float4* Pr = (const float4*)(Pb + (long)r * 64);
    const float4* Qc = (const float4*)(Qb + (long)c * 64);
    int swz = (lane & 15) << 3;
    // phase A: layer1 + silu -> bf16 A-tile (row = lane)
    #pragma unroll
    for (int kc = 0; kc < 16; ++kc) {
        float4 pv = Pr[kc], qv = Qc[kc];
        float h0 = silu_f(pv.x + qv.x + rad*w1t[4*kc+0] + d0*w1t[64+4*kc+0]);
        float h1 = silu_f(pv.y + qv.y + rad*w1t[4*kc+1] + d0*w1t[64+4*kc+1]);
        float h2 = silu_f(pv.z + qv.z + rad*w1t[4*kc+2] + d0*w1t[64+4*kc+2]);
        float h3 = silu_f(pv.w + qv.w + rad*w1t[4*kc+3] + d0*w1t[64+4*kc+3]);
        uint2 pk = make_uint2(bfr(h0) | (bfr(h1) << 16), bfr(h2) | (bfr(h3) << 16));
        *(uint2*)((char*)Aw + lane*128 + ((8*kc) ^ swz)) = pk;
    }
    __syncthreads();
    // B fragments (precomputed order, coalesced 16B loads)
    ABfrag bf[4][2];
    #pragma unroll
    for (int n = 0; n < 4; ++n)
        #pragma unroll
        for (int s = 0; s < 2; ++s)
            bf[n][s].u4 = *(const uint4*)(w2f + ((n*2 + s)*64 + lane)*8);
    int r0 = lane & 15, g = lane >> 4;
    f32x4 acc[4][4];
    #pragma unroll
    for (int t = 0; t < 4; ++t)
        #pragma unroll
        for (int n = 0; n < 4; ++n)
            acc[t][n] = (f32x4){0.f, 0.f, 0.f, 0.f};
    #pragma unroll
    for (int t = 0; t < 4; ++t) {
        #pragma unroll
        for (int s = 0; s < 2; ++s) {
            int boff = 16*g + 64*s;
            ABfrag af;
            af.u2[0] = *(uint2*)((char*)Aw + (16*t + r0)*128 + ( boff      ^ (r0 << 3)));
            af.u2[1] = *(uint2*)((char*)Aw + (16*t + r0)*128 + ((boff + 8) ^ (r0 << 3)));
            #pragma unroll
            for (int n = 0; n < 4; ++n)
                acc[t][n] = __builtin_amdgcn_mfma_f32_16x16x32_bf16(
                    af.s8, bf[n][s].s8, acc[t][n], 0, 0, 0);
        }
    }
    // epilogue: +bias, silu, bf16 -> M_lds[feat][edge]
    #pragma unroll
    for (int n = 0; n < 4; ++n) {
        float b2v = b2[16*n + r0];
        #pragma unroll
        for (int t = 0; t < 4; ++t) {
            f32x4 z = acc[t][n];
            u32 p0 = bfr(silu_f(z[0] + b2v)) | (bfr(silu_f(z[1] + b2v)) << 16);
            u32 p1 = bfr(silu_f(z[2] + b2v)) | (bfr(silu_f(z[3] + b2v)) << 16);
            *(uint2*)((char*)Mw + (16*n + r0)*136 + 32*t + 8*g) = make_uint2(p0, p1);
        }
    }
    __syncthreads();
    // aggregation: lane = feature; walk 64 sorted edges, flush per run (coalesced)
    float racc = 0.0f;
    int cur = __builtin_amdgcn_readfirstlane(__shfl(r, 0));
    #pragma unroll
    for (int ch = 0; ch < 16; ++ch) {
        uint2 mm = *(uint2*)((char*)Mw + lane*136 + 8*ch);
        #pragma unroll
        for (int q = 0; q < 4; ++q) {
            int ee = 4*ch + q;
            u32 hu = ((q & 2) ? mm.y : mm.x) >> ((q & 1) * 16);
            float v = bff(hu & 0xffffu);
            int rr = __builtin_amdgcn_readfirstlane(__shfl(r, ee));
            if (rr != cur) {
                atomicAdd(&agg[(long)cur*64 + lane], racc);
                racc = 0.0f; cur = rr;
            }
            racc += v;
        }
    }
    atomicAdd(&agg[(long)cur*64 + lane], racc);
}

// ---------------- node MLP: h += silu([h, agg/100] @ w1 + b1) @ w2 + b2
__global__ __launch_bounds__(256, 2) void k_node(float* __restrict__ h64,
        const float* __restrict__ agg,
        const float* __restrict__ w1, const float* __restrict__ b1,
        const float* __restrict__ w2, const float* __restrict__ b2) {
    int n = blockIdx.x * 256 + threadIdx.x;
    if (n >= NN) return;
    const float4* h4 = (const float4*)(h64 + (long)n * 64);
    const float4* a4 = (const float4*)(agg + (long)n * 64);
    float in[64];
    #pragma unroll
    for (int c = 0; c < 16; ++c) {
        float4 v = h4[c];
        in[4*c+0]=v.x; in[4*c+1]=v.y; in[4*c+2]=v.z; in[4*c+3]=v.w;
    }
    float hid[64];
    #pragma unroll
    for (int j = 0; j < 64; ++j) hid[j] = b1[j];
    #pragma unroll
    for (int k = 0; k < 64; ++k) {
        #pragma unroll
        for (int j = 0; j < 64; ++j) hid[j] = fmaf(in[k], w1[k*64+j], hid[j]);
    }
    const float* w1b = w1 + 64*64;
    #pragma unroll
    for (int c = 0; c < 16; ++c) {
        float4 v = a4[c];
        float s0 = v.x*0.01f, s1 = v.y*0.01f, s2 = v.z*0.01f, s3 = v.w*0.01f;
        #pragma unroll
        for (int j = 0; j < 64; ++j) hid[j] = fmaf(s0, w1b[(4*c+0)*64+j], hid[j]);
        #pragma unroll
        for (int j = 0; j < 64; ++j) hid[j] = fmaf(s1, w1b[(4*c+1)*64+j], hid[j]);
        #pragma unroll
        for (int j = 0; j < 64; ++j) hid[j] = fmaf(s2, w1b[(4*c+2)*64+j], hid[j]);
        #pragma unroll
        for (int j = 0; j < 64; ++j) hid[j] = fmaf(s3, w1b[(4*c+3)*64+j], hid[j]);
    }
    #pragma unroll
    for (int j = 0; j < 64; ++j) hid[j] = silu_f(hid[j]);
    float acc[64];
    #pragma unroll
    for (int j = 0; j < 64; ++j) acc[j] = b2[j];
    #pragma unroll
    for (int k = 0; k < 64; ++k) {
        #pragma unroll
        for (int j = 0; j < 64; ++j) acc[j] = fmaf(hid[k], w2[k*64+j], acc[j]);
    }
    float4* o4 = (float4*)(h64 + (long)n * 64);
    #pragma unroll
    for (int c = 0; c < 16; ++c) {
        float4 v = o4[c];
        v.x += acc[4*c+0]; v.y += acc[4*c+1]; v.z += acc[4*c+2]; v.w += acc[4*c+3];
        o4[c] = v;
    }
}

// ---------------- coordinate update: layer2 via MFMA, phi via shfl butterfly
__global__ __launch_bounds__(256, 2) void k_coord(
        const float* __restrict__ Pb, const float* __restrict__ Qb,
        const float* __restrict__ radial, const float* __restrict__ dist0,
        const int* __restrict__ rowS, const int* __restrict__ colS,
        const float* __restrict__ w1t, const u16* __restrict__ w2f,
        const float* __restrict__ b2, const float* __restrict__ w3,
        const float* __restrict__ x_old, float* __restrict__ x_new) {
    __shared__ u16 A_lds[4][4096];
    int tid = threadIdx.x;
    int w = tid >> 6, lane = tid & 63;
    int e = blockIdx.x * 256 + w * 64 + lane;
    u16* Aw = A_lds[w];
    int r = rowS[e], c = colS[e];
    float rad = radial[e], d0 = dist0[e];
    const float4* Pr = (const float4*)(Pb + (long)r * 64);
    const float4* Qc = (const float4*)(Qb + (long)c * 64);
    int swz = (lane & 15) << 3;
    #pragma unroll
    for (int kc = 0; kc < 16; ++kc) {
        float4 pv = Pr[kc], qv = Qc[kc];
        float h0 = silu_f(pv.x + qv.x + rad*w1t[4*kc+0] + d0*w1t[64+4*kc+0]);
        float h1 = silu_f(pv.y + qv.y + rad*w1t[4*kc+1] + d0*w1t[64+4*kc+1]);
        float h2 = silu_f(pv.z + qv.z + rad*w1t[4*kc+2] + d0*w1t[64+4*kc+2]);
        float h3 = silu_f(pv.w + qv.w + rad*w1t[4*kc+3] + d0*w1t[64+4*kc+3]);
        uint2 pk = make_uint2(bfr(h0) | (bfr(h1) << 16), bfr(h2) | (bfr(h3) << 16));
        *(uint2*)((char*)Aw + lane*128 + ((8*kc) ^ swz)) = pk;
    }
    __syncthreads();
    ABfrag bf[4][2];
    #pragma unroll
    for (int n = 0; n < 4; ++n)
        #pragma unroll
        for (int s = 0; s < 2; ++s)
            bf[n][s].u4 = *(const uint4*)(w2f + ((n*2 + s)*64 + lane)*8);
    int r0 = lane & 15, g = lane >> 4;
    f32x4 acc[4][4];
    #pragma unroll
    for (int t = 0; t < 4; ++t)
        #pragma unroll
        for (int n = 0; n < 4; ++n)
            acc[t][n] = (f32x4){0.f, 0.f, 0.f, 0.f};
    #pragma unroll
    for (int t = 0; t < 4; ++t) {
        #pragma unroll
        for (int s = 0; s < 2; ++s) {
            int boff = 16*g + 64*s;
            ABfrag af;
            af.u2[0] = *(uint2*)((char*)Aw + (16*t + r0)*128 + ( boff      ^ (r0 << 3)));
            af.u2[1] = *(uint2*)((char*)Aw + (16*t + r0)*128 + ((boff + 8) ^ (r0 << 3)));
            #pragma unroll
            for (int n = 0; n < 4; ++n)
                acc[t][n] = __builtin_amdgcn_mfma_f32_16x16x32_bf16(
                    af.s8, bf[n][s].s8, acc[t][n], 0, 0, 0);
        }
    }
    // phi partials: sum over this lane's 4 feature columns
    float w3v[4], b2v[4];
    #pragma unroll
    for (int n = 0; n < 4; ++n) { w3v[n] = w3[16*n + r0]; b2v[n] = b2[16*n + r0]; }
    float ph[16];
    #pragma unroll
    for (int t = 0; t < 4; ++t)
        #pragma unroll
        for (int q = 0; q < 4; ++q) {
            float s = 0.f;
            #pragma unroll
            for (int n = 0; n < 4; ++n)
                s = fmaf(silu_f(acc[t][n][q] + b2v[n]), w3v[n], s);
            ph[t*4 + q] = s;
        }
    // reduce across the 16-lane feature group
    #pragma unroll
    for (int d = 1; d < 16; d <<= 1)
        #pragma unroll
        for (int i = 0; i < 16; ++i) ph[i] += __shfl_xor(ph[i], d);
    __syncthreads();                    // A_lds reads complete everywhere
    float* phl = (float*)Aw;            // reuse A tile for phi[64]
    if (r0 == 0) {
        #pragma unroll
        for (int t = 0; t < 4; ++t)
            #pragma unroll
            for (int q = 0; q < 4; ++q)
                phl[16*t + 4*g + q] = ph[t*4 + q];
    }
    __syncthreads();
    float phi = phl[lane] * 0.01f;      // 1/NORM_FACTOR folded in
    float dx = x_old[r*3+0] - x_old[c*3+0];
    float dy = x_old[r*3+1] - x_old[c*3+1];
    float dz = x_old[r*3+2] - x_old[c*3+2];
    float inv = phi / (sqrtf(rad + 1e-8f) + 1.0f);
    float tx = dx * inv, ty = dy * inv, tz = dz * inv;
    // wave-level segmented reduction over equal-row runs (rows sorted)
    int rprev = __shfl_up(r, 1);
    bool head = (lane == 0) || (rprev != r);
    unsigned long long hm = __ballot(head);
    int runid = __popcll(hm & ((2ull << lane) - 1ull));
    #pragma unroll
    for (int d = 1; d < 64; d <<= 1) {
        float ox = __shfl_up(tx, d);
        float oy = __shfl_up(ty, d);
        float oz = __shfl_up(tz, d);
        int orid = __shfl_up(runid, d);
        if (lane >= d && orid == runid) { tx += ox; ty += oy; tz += oz; }
    }
    int rid_next = __shfl_down(runid, 1);
    bool tail = (lane == 63) || (rid_next != runid);
    if (tail) {
        atomicAdd(&x_new[r*3+0], tx);
        atomicAdd(&x_new[r*3+1], ty);
        atomicAdd(&x_new[r*3+2], tz);
    }
}

// ---------------- output projection: out = h64 @ out_w + out_b
__global__ __launch_bounds__(256, 4) void k_out(const float* __restrict__ h64,
        const float* __restrict__ w, const float* __restrict__ b,
        float* __restrict__ out) {
    int n = blockIdx.x * 256 + threadIdx.x;
    if (n >= NN) return;
    float acc[16];
    #pragma unroll
    for (int j = 0; j < 16; ++j) acc[j] = b[j];
    const float4* h4 = (const float4*)(h64 + (long)n*64);
    #pragma unroll
    for (int c = 0; c < 16; ++c) {
        float4 v = h4[c];
        float vv[4] = {v.x, v.y, v.z, v.w};
        #pragma unroll
        for (int t = 0; t < 4; ++t) {
            #pragma unroll
            for (int j = 0; j < 16; ++j)
                acc[j] = fmaf(vv[t], w[(4*c+t)*16 + j], acc[j]);
        }
    }
    float4* o4 = (float4*)(out + (long)n*16);
    #pragma unroll
    for (int cq = 0; cq < 4; ++cq)
        o4[cq] = make_float4(acc[4*cq+0],acc[4*cq+1],acc[4*cq+2],acc[4*cq+3]);
}

extern "C" void kernel_launch(void* const* d_in, const int* in_sizes, int n_in,
                              void* d_out, int out_size, void* d_ws, size_t ws_size,
                              hipStream_t stream) {
    const float* h_in  = (const float*)d_in[0];
    const float* x_in  = (const float*)d_in[1];
    const int*   row   = (const int*)d_in[2];
    const int*   col   = (const int*)d_in[3];
    const float* emb_w = (const float*)d_in[4];
    const float* emb_b = (const float*)d_in[5];
    const float* out_w = (const float*)d_in[6];
    const float* out_b = (const float*)d_in[7];
    const float* e_w1  = (const float*)d_in[8];
    const float* e_b1  = (const float*)d_in[9];
    const float* e_w2  = (const float*)d_in[10];
    const float* e_b2  = (const float*)d_in[11];
    const float* n_w1  = (const float*)d_in[12];
    const float* n_b1  = (const float*)d_in[13];
    const float* n_w2  = (const float*)d_in[14];
    const float* n_b2  = (const float*)d_in[15];
    const float* q_w1  = (const float*)d_in[16];
    const float* q_b1  = (const float*)d_in[17];
    const float* q_w2  = (const float*)d_in[18];
    const float* q_b2  = (const float*)d_in[19];
    const float* q_w3  = (const float*)d_in[20];

    size_t need = 49152 + ((size_t)NN*64*4 + (size_t)NE*2 + (size_t)NN*3
                   + (size_t)NE*2 + (size_t)NN*2 + 64) * sizeof(float);
    if (ws_size < need) return;

    u16*   w2f   = (u16*)d_ws;                       // 6*4096 bf16 frags (48 KB)
    float* fb    = (float*)((char*)d_ws + 49152);
    float* h64   = fb;                               // N*64
    float* Pb    = h64   + (size_t)NN*64;
    float* Qb    = Pb    + (size_t)NN*64;
    float* agg   = Qb    + (size_t)NN*64;
    float* d0S   = agg   + (size_t)NN*64;            // E (sorted)
    float* radS  = d0S   + (size_t)NE;               // E (sorted)
    float* xA    = radS  + (size_t)NE;               // N*3
    int*   rowS  = (int*)(xA + (size_t)NN*3);        // E
    int*   colS  = rowS  + (size_t)NE;               // E
    int*   deg   = colS  + (size_t)NE;               // N
    int*   base  = deg   + (size_t)NN;               // N

    float* out_h = (float*)d_out;
    float* out_x = out_h + (size_t)NN*16;

    dim3 th(256);
    dim3 nb((NN + 255)/256);
    dim3 eb(NE/256);
    dim3 pqb((NN + 63)/64);

    // setup: sort edges by row; convert w2 matrices to B-frag bf16
    hipMemsetAsync(deg, 0, (size_t)NN*sizeof(int), stream);
    k_hist<<<eb, th, 0, stream>>>(row, deg);
    k_scan<<<1, th, 0, stream>>>(deg, base);
    k_scatter<<<eb, th, 0, stream>>>(row, col, base, rowS, colS);
    k_wconv<<<96, th, 0, stream>>>(e_w2, q_w2, w2f);

    k_radial<<<eb, th, 0, stream>>>(x_in, rowS, colS, d0S);
    k_embed<<<nb, th, 0, stream>>>(h_in, emb_w, emb_b, h64);

    for (int b = 0; b < 2; ++b) {
        const float* x_old;
        float*       x_new;
        const float* radp;
        if (b == 0) {
            x_old = x_in;  x_new = xA;    radp = d0S;
        } else {
            x_old = xA;    x_new = out_x; radp = radS;
            k_radial<<<eb, th, 0, stream>>>(x_old, rowS, colS, radS);
        }
        for (int i = 0; i < 2; ++i) {
            int l = b*2 + i;
            k_pq<<<pqb, th, 0, stream>>>(h64, e_w1 + (size_t)l*130*64,
                                         e_b1 + (size_t)l*64, Pb, Qb);
            hipMemsetAsync(agg, 0, (size_t)NN*64*sizeof(float), stream);
            k_edge<<<eb, th, 0, stream>>>(Pb, Qb, radp, d0S, rowS, colS,
                    e_w1 + (size_t)l*130*64 + 128*64,
                    w2f + (size_t)l*4096,
                    e_b2 + (size_t)l*64, agg);
            k_node<<<nb, th, 0, stream>>>(h64, agg,
                    n_w1 + (size_t)l*128*64, n_b1 + (size_t)l*64,
                    n_w2 + (size_t)l*64*64, n_b2 + (size_t)l*64);
        }
        k_pq<<<pqb, th, 0, stream>>>(h64, q_w1 + (size_t)b*130*64,
                                     q_b1 + (size_t)b*64, Pb, Qb);
        hipMemcpyAsync(x_new, x_old, (size_t)NN*3*sizeof(float),
                       hipMemcpyDeviceToDevice, stream);
        k_coord<<<eb, th, 0, stream>>>(Pb, Qb, radp, d0S, rowS, colS,
                q_w1 + (size_t)b*130*64 + 128*64,
                w2f + (size_t)(4 + b)*4096,
                q_b2 + (size_t)b*64, q_w3 + (size_t)b*64, x_old, x_new);
    }
    k_out<<<nb, th, 0, stream>>>(h64, out_w, out_b, out_h);
}